// Round 16
// baseline (150.325 us; speedup 1.0000x reference)
//
#include <hip/hip_runtime.h>
#include <math.h>

#define T_DIM 2048
#define C_DIM 1024
#define B_DIM 8
#define TB    32
#define KROW  72      // bf16 elems per Kc/Qc row (64 + 8 pad)  [fallback kernel]
#define PROW  296     // bf16 elems per P row (288 + 8 pad)

typedef float f32x4 __attribute__((ext_vector_type(4)));
typedef short s16x8 __attribute__((ext_vector_type(8)));

__device__ __forceinline__ unsigned short f2bf(float x) {
    union { float f; unsigned u; } v; v.f = x;
    unsigned r = v.u + 0x7fffu + ((v.u >> 16) & 1u);
    return (unsigned short)(r >> 16);
}
__device__ __forceinline__ unsigned pk2(float a, float b) {
    return (unsigned)f2bf(a) | ((unsigned)f2bf(b) << 16);
}

// async 16B/lane global->LDS DMA (wave-uniform LDS base + lane*16; per-lane global src)
__device__ __forceinline__ void gll16(const void* g, void* l) {
    __builtin_amdgcn_global_load_lds(
        (const __attribute__((address_space(1))) unsigned int*)g,
        (__attribute__((address_space(3))) unsigned int*)l,
        16, 0, 0);
}

// ============ pre-pass A: K f32 -> fragment-major bf16 Kt[b][tile][kk][lane][8] ============
// elem = K[b][tile*16+(l&15)][kk*32+(l>>4)*8+j]  [r5/r13-verified]
__global__ __launch_bounds__(256)
void tile_k(const float* __restrict__ K, unsigned short* __restrict__ Kt)
{
    const int tile = blockIdx.x;      // 0..127
    const int b    = blockIdx.y;
    const int tid  = threadIdx.x;
    const int w = tid >> 6, l = tid & 63, g = l >> 4, ln = l & 15;
    const float* src_row = K + (size_t)(b * T_DIM + tile * 16 + ln) * C_DIM;
#pragma unroll
    for (int kki = 0; kki < 8; ++kki) {
        const int kk = kki * 4 + w;
        const float4* p = (const float4*)(src_row + kk * 32 + g * 8);
        float4 x = p[0], y = p[1];
        uint4 o;
        o.x = pk2(x.x, x.y); o.y = pk2(x.z, x.w);
        o.z = pk2(y.x, y.y); o.w = pk2(y.z, y.w);
        *(uint4*)(Kt + (size_t)(((b * 128 + tile) * 32 + kk) * 64 + l) * 8) = o;
    }
}

// ============ pre-pass B: V f32 -> bf16, fragment-major Vtt OR row-major Vt (verified) ============
__global__ __launch_bounds__(256)
void transpose_vx(const float* __restrict__ V, unsigned short* __restrict__ out,
                  int frag_mode)
{
    __shared__ float buf[64 * 67];
    const int t0 = blockIdx.x * 64;
    const int c0 = blockIdx.y * 64;
    const int b  = blockIdx.z;
    const float* Vb = V + (size_t)b * T_DIM * C_DIM;

    for (int i = threadIdx.x; i < 64 * 64; i += 256) {
        const int r = i >> 6, c = i & 63;
        buf[r * 67 + c] = Vb[(size_t)(t0 + r) * C_DIM + c0 + c];
    }
    __syncthreads();
    const int t8 = threadIdx.x & 7;   // 8-t segment
    const int cl = threadIdx.x >> 3;  // 0..31
#pragma unroll
    for (int half = 0; half < 2; ++half) {
        const int c_loc = cl + half * 32;
        float v[8];
#pragma unroll
        for (int j = 0; j < 8; ++j) v[j] = buf[(t8 * 8 + j) * 67 + c_loc];
        uint4 o;
        o.x = pk2(v[0], v[1]); o.y = pk2(v[2], v[3]);
        o.z = pk2(v[4], v[5]); o.w = pk2(v[6], v[7]);
        if (frag_mode) {
            const int ct = (c0 + c_loc) >> 4, lnv = c_loc & 15;
            const int g = t8 & 3, sg = (t0 >> 5) + (t8 >> 2);
            *(uint4*)(out + (size_t)(((b * 64 + ct) * 64 + sg) * 64 + g * 16 + lnv) * 8) = o;
        } else {
            *(uint4*)(out + (size_t)(b * C_DIM + c0 + c_loc) * T_DIM + t0 + t8 * 8) = o;
        }
    }
}

// ============ banded attention: Q preloaded to VGPRs (one-time f32 gather); K-only staging ============
// 256 thr = 4 waves (th = t-half of 32-row tile, sh = s-half / c-split).
__global__ __launch_bounds__(256, 2)
void attn_band_tiled(const float* __restrict__ Qf,
                     const unsigned short* __restrict__ Kt,
                     const unsigned short* __restrict__ Vtt,
                     const float* __restrict__ Mask, const int* __restrict__ m_ptr,
                     float* __restrict__ wsrow)
{
    // SMEM map (shorts):  phase1: Kbuf = [0, 18432)  (2 bufs x 18 frags x 512)
    //                     phase2/3: P = [0, 9472); Vbuf = [9728, 30208) (2 x 20 x 512)
    __shared__ __align__(16) short SMEM[30208];   // 60,416 B
    __shared__ float pmax[64], psum[64], red[64];
    short* Kbuf = SMEM;
    short* P    = SMEM;
    short* Vbuf = SMEM + 9728;

    // XCD-bijective swizzle: each XCD owns one batch's contiguous t-range
    const int h = blockIdx.x;
    const int logical = (h & 7) * 64 + (h >> 3);
    const int b  = logical >> 6;
    const int t0 = (logical & 63) * TB;

    const int tid = threadIdx.x;
    const int w = tid >> 6, lane = tid & 63, g = lane >> 4, ln = lane & 15;
    const int th = w >> 1, sh = w & 1;
    const int m  = m_ptr[0];

    const int s_lo = max(0, t0 - m);
    const int s_hi = min(T_DIM - 1, t0 + TB - 1 + m);
    const int sg0  = s_lo >> 5;               // 32-aligned by construction

    const unsigned short* Ktb = Kt  + (size_t)b * 128 * 32 * 512;
    const unsigned short* Vtb = Vtt + (size_t)b * 64 * 64 * 512;

    // ---- Q preload: 32 aq fragments gathered ONCE from f32 Q, packed to bf16 in VGPRs ----
    s16x8 aqr[32];
    {
        const float* qrow = Qf + (size_t)(b * T_DIM + t0 + th * 16 + ln) * C_DIM;
#pragma unroll
        for (int kk = 0; kk < 32; ++kk) {
            const float4* qp = (const float4*)(qrow + kk * 32 + g * 8);
            float4 qx = qp[0], qy = qp[1];
            uint4 a;
            a.x = pk2(qx.x, qx.y); a.y = pk2(qx.z, qx.w);
            a.z = pk2(qy.x, qy.y); a.w = pk2(qy.z, qy.w);
            aqr[kk] = *(s16x8*)&a;
        }
    }

    // ---- phase 1: E = Q.K^T; per kk stage 18 K frags (contiguous), dbuf, 1 barrier/iter ----
    f32x4 E[9];
    f32x4 zed = {0.f, 0.f, 0.f, 0.f};
#pragma unroll
    for (int i = 0; i < 9; ++i) E[i] = zed;

    // wave w stages frags f = 5w..5w+4 (f<18): K tile min(sg0*2+f,127)
#define STAGE1K(KN, NB)                                                             \
    {                                                                               \
        short* dstb = Kbuf + (NB) * 9216;                                           \
        _Pragma("unroll")                                                           \
        for (int f5 = 0; f5 < 5; ++f5) {                                            \
            const int f = w * 5 + f5;                                               \
            if (f < 18)                                                             \
                gll16(Ktb + ((size_t)(min(sg0 * 2 + f, 127) * 32 + (KN)) * 64 + lane) * 8, \
                      dstb + f * 512);                                              \
        }                                                                           \
    }

    STAGE1K(0, 0);
    __syncthreads();

#pragma unroll
    for (int kk = 0; kk < 32; ++kk) {       // FULL unroll: aqr[kk] stays in registers
        const int cur = kk & 1;
        if (kk < 31) STAGE1K(kk + 1, cur ^ 1);
        const short* cb = Kbuf + cur * 9216;
#pragma unroll
        for (int i = 0; i < 9; ++i) {
            s16x8 bk = *(const s16x8*)(cb + (sh * 9 + i) * 512 + lane * 8);
            E[i] = __builtin_amdgcn_mfma_f32_16x16x32_bf16(aqr[kk], bk, E[i], 0, 0, 0);
        }
        __syncthreads();
    }

    // ---- phase 2: exact softmax (cross-wave over the two s-halves) ----
    const float scale = 0.03125f;   // 1/sqrt(1024)
    const int rowb = th * 16 + g * 4;
    float lm[4];
#pragma unroll
    for (int r = 0; r < 4; ++r) lm[r] = -INFINITY;
    const int s_base = s_lo + sh * 144 + ln;
#pragma unroll
    for (int i = 0; i < 9; ++i) {
        const int s = s_base + i * 16;
#pragma unroll
        for (int r = 0; r < 4; ++r) {
            const int t = t0 + rowb + r;
            int d = t - s; d = d < 0 ? -d : d;
            const bool valid = (s <= s_hi) && (d <= m);
            float e = valid ? E[i][r] : -INFINITY;
            E[i][r] = e;
            lm[r] = fmaxf(lm[r], e);
        }
    }
#pragma unroll
    for (int r = 0; r < 4; ++r)
#pragma unroll
        for (int dd = 1; dd < 16; dd <<= 1) lm[r] = fmaxf(lm[r], __shfl_xor(lm[r], dd));
    if (ln == 0) {
#pragma unroll
        for (int r = 0; r < 4; ++r) pmax[sh * 32 + rowb + r] = lm[r];
    }
    __syncthreads();
    float Mr[4], sum[4];
#pragma unroll
    for (int r = 0; r < 4; ++r) {
        Mr[r] = fmaxf(pmax[rowb + r], pmax[32 + rowb + r]) * scale;
        sum[r] = 0.f;
    }
#pragma unroll
    for (int i = 0; i < 9; ++i)
#pragma unroll
        for (int r = 0; r < 4; ++r) {
            float e = __expf(E[i][r] * scale - Mr[r]);   // -inf -> 0 exactly
            E[i][r] = e;
            sum[r] += e;
        }
#pragma unroll
    for (int r = 0; r < 4; ++r)
#pragma unroll
        for (int dd = 1; dd < 16; dd <<= 1) sum[r] += __shfl_xor(sum[r], dd);
    if (ln == 0) {
#pragma unroll
        for (int r = 0; r < 4; ++r) psum[sh * 32 + rowb + r] = sum[r];
    }
    __syncthreads();
    float inv[4];
#pragma unroll
    for (int r = 0; r < 4; ++r) inv[r] = 1.0f / (psum[rowb + r] + psum[32 + rowb + r]);
#pragma unroll
    for (int i = 0; i < 9; ++i) {
        const int col = sh * 144 + i * 16 + ln;
#pragma unroll
        for (int r = 0; r < 4; ++r)
            P[(rowb + r) * PROW + col] = (short)f2bf(E[i][r] * inv[r]);
    }
    __syncthreads();

    // ---- phase 3: O = P @ V; per q two staged steps (kg 0-4, 5-8), dbuf, 1 barrier/step ----
    s16x8 pa[9];
#pragma unroll
    for (int kg = 0; kg < 9; ++kg)
        pa[kg] = *(const s16x8*)(P + (th * 16 + ln) * PROW + kg * 32 + g * 8);

    int sgc[9];
#pragma unroll
    for (int kg = 0; kg < 9; ++kg) sgc[kg] = min(sg0 + kg, 63);

    float maskv[4], rmax[4];
#pragma unroll
    for (int r = 0; r < 4; ++r) {
        maskv[r] = Mask[(size_t)b * T_DIM + t0 + rowb + r];
        rmax[r]  = -INFINITY;
    }

    // wave w stages ct = 4q+w, kg in [kgbase, kgbase+KG): slot (w*KG + e)
#define STAGE3(S, NB)                                                               \
    {                                                                               \
        const int q_ = (S) >> 1;                                                    \
        short* dstb = Vbuf + (NB) * 10240;                                          \
        const int ct_ = q_ * 4 + w;                                                 \
        if (((S) & 1) == 0) {                                                       \
            _Pragma("unroll")                                                       \
            for (int e = 0; e < 5; ++e)                                             \
                gll16(Vtb + ((size_t)(ct_ * 64 + sgc[e]) * 64 + lane) * 8,          \
                      dstb + (w * 5 + e) * 512);                                    \
        } else {                                                                    \
            _Pragma("unroll")                                                       \
            for (int e = 0; e < 4; ++e)                                             \
                gll16(Vtb + ((size_t)(ct_ * 64 + sgc[5 + e]) * 64 + lane) * 8,      \
                      dstb + (w * 4 + e) * 512);                                    \
        }                                                                           \
    }

    STAGE3(0, 0);
    __syncthreads();

    f32x4 O0 = zed, O1 = zed;
#pragma unroll 2
    for (int s = 0; s < 32; ++s) {
        const int cur = s & 1;
        if (s < 31) STAGE3(s + 1, cur ^ 1);
        const short* vb = Vbuf + cur * 10240;
        if ((s & 1) == 0) {
            O0 = zed; O1 = zed;
#pragma unroll
            for (int e = 0; e < 5; ++e) {
                s16x8 bv0 = *(const s16x8*)(vb + ((sh * 2    ) * 5 + e) * 512 + lane * 8);
                s16x8 bv1 = *(const s16x8*)(vb + ((sh * 2 + 1) * 5 + e) * 512 + lane * 8);
                O0 = __builtin_amdgcn_mfma_f32_16x16x32_bf16(pa[e], bv0, O0, 0, 0, 0);
                O1 = __builtin_amdgcn_mfma_f32_16x16x32_bf16(pa[e], bv1, O1, 0, 0, 0);
            }
        } else {
#pragma unroll
            for (int e = 0; e < 4; ++e) {
                s16x8 bv0 = *(const s16x8*)(vb + ((sh * 2    ) * 4 + e) * 512 + lane * 8);
                s16x8 bv1 = *(const s16x8*)(vb + ((sh * 2 + 1) * 4 + e) * 512 + lane * 8);
                O0 = __builtin_amdgcn_mfma_f32_16x16x32_bf16(pa[5 + e], bv0, O0, 0, 0, 0);
                O1 = __builtin_amdgcn_mfma_f32_16x16x32_bf16(pa[5 + e], bv1, O1, 0, 0, 0);
            }
#pragma unroll
            for (int r = 0; r < 4; ++r) {
                rmax[r] = fmaxf(rmax[r], O0[r] * maskv[r]);
                rmax[r] = fmaxf(rmax[r], O1[r] * maskv[r]);
            }
        }
        __syncthreads();
    }

#pragma unroll
    for (int r = 0; r < 4; ++r)
#pragma unroll
        for (int dd = 1; dd < 16; dd <<= 1) rmax[r] = fmaxf(rmax[r], __shfl_xor(rmax[r], dd));
    if (ln == 0) {
#pragma unroll
        for (int r = 0; r < 4; ++r) red[sh * 32 + rowb + r] = rmax[r];
    }
    __syncthreads();
    if (tid < 32)
        wsrow[(size_t)b * T_DIM + t0 + tid] = fmaxf(red[tid], red[32 + tid]);
}

// ============ fallback (round-1, verified): K/V staged per block, Vt row-major ============
__global__ __launch_bounds__(256, 2)
void attn_band_mfma(const float* __restrict__ Q, const float* __restrict__ K,
                    const unsigned short* __restrict__ Vt,
                    const float* __restrict__ Mask, const int* __restrict__ m_ptr,
                    float* __restrict__ wsrow)
{
    __shared__ __align__(16) char smem_raw[57600];
    short* SM = (short*)smem_raw;
    short* Kc = SM;
    short* Qc = SM + 288 * KROW;
    short* P  = SM;
    short* Vl = SM + 32 * PROW;
    float* pmax = (float*)(smem_raw + 56832);
    float* psum = pmax + 64;
    float* red  = psum + 64;

    const int h = blockIdx.x;
    const int logical = (h & 7) * 64 + (h >> 3);
    const int b  = logical >> 6;
    const int t0 = (logical & 63) * TB;

    const int tid = threadIdx.x;
    const int w = tid >> 6, lane = tid & 63, g = lane >> 4, ln = lane & 15;
    const int th = w >> 1, sh = w & 1;
    const int m  = m_ptr[0];

    const int s_lo = max(0, t0 - m);
    const int s_hi = min(T_DIM - 1, t0 + TB - 1 + m);

    const float* Qb = Q + (size_t)b * T_DIM * C_DIM;
    const float* Kb = K + (size_t)b * T_DIM * C_DIM;
    const unsigned short* Vtb = Vt + (size_t)b * C_DIM * T_DIM;

    f32x4 E[9];
    f32x4 zed = {0.f, 0.f, 0.f, 0.f};
#pragma unroll
    for (int i = 0; i < 9; ++i) E[i] = zed;

    for (int cc = 0; cc < C_DIM / 64; ++cc) {
        const int c0 = cc * 64;
        __syncthreads();
        for (int u = tid; u < 288 * 8; u += 256) {
            const int su = u >> 3, un = u & 7;
            const int s = min(s_lo + su, T_DIM - 1);
            const float4* src = (const float4*)(Kb + (size_t)s * C_DIM + c0 + un * 8);
            float4 x = src[0], y = src[1];
            uint4 o; o.x = pk2(x.x, x.y); o.y = pk2(x.z, x.w);
            o.z = pk2(y.x, y.y); o.w = pk2(y.z, y.w);
            *(uint4*)(Kc + su * KROW + un * 8) = o;
        }
        {
            const int su = tid >> 3, un = tid & 7;
            const float4* src = (const float4*)(Qb + (size_t)(t0 + su) * C_DIM + c0 + un * 8);
            float4 x = src[0], y = src[1];
            uint4 o; o.x = pk2(x.x, x.y); o.y = pk2(x.z, x.w);
            o.z = pk2(y.x, y.y); o.w = pk2(y.z, y.w);
            *(uint4*)(Qc + su * KROW + un * 8) = o;
        }
        __syncthreads();
        s16x8 aq[2];
#pragma unroll
        for (int kk = 0; kk < 2; ++kk)
            aq[kk] = *(const s16x8*)(Qc + (th * 16 + ln) * KROW + kk * 32 + g * 8);
#pragma unroll
        for (int i = 0; i < 9; ++i) {
            const int srow2 = (sh * 9 + i) * 16 + ln;
#pragma unroll
            for (int kk = 0; kk < 2; ++kk) {
                s16x8 bk = *(const s16x8*)(Kc + srow2 * KROW + kk * 32 + g * 8);
                E[i] = __builtin_amdgcn_mfma_f32_16x16x32_bf16(aq[kk], bk, E[i], 0, 0, 0);
            }
        }
    }

    const float scale = 0.03125f;
    const int rowb = th * 16 + g * 4;
    float lm[4];
#pragma unroll
    for (int r = 0; r < 4; ++r) lm[r] = -INFINITY;
    const int s_base = s_lo + sh * 144 + ln;
#pragma unroll
    for (int i = 0; i < 9; ++i) {
        const int s = s_base + i * 16;
#pragma unroll
        for (int r = 0; r < 4; ++r) {
            const int t = t0 + rowb + r;
            int d = t - s; d = d < 0 ? -d : d;
            const bool valid = (s <= s_hi) && (d <= m);
            float e = valid ? E[i][r] : -INFINITY;
            E[i][r] = e;
            lm[r] = fmaxf(lm[r], e);
        }
    }
#pragma unroll
    for (int r = 0; r < 4; ++r)
#pragma unroll
        for (int dd = 1; dd < 16; dd <<= 1) lm[r] = fmaxf(lm[r], __shfl_xor(lm[r], dd));
    if (ln == 0) {
#pragma unroll
        for (int r = 0; r < 4; ++r) pmax[sh * 32 + rowb + r] = lm[r];
    }
    __syncthreads();
    float Mr[4], sum[4];
#pragma unroll
    for (int r = 0; r < 4; ++r) {
        Mr[r] = fmaxf(pmax[rowb + r], pmax[32 + rowb + r]) * scale;
        sum[r] = 0.f;
    }
#pragma unroll
    for (int i = 0; i < 9; ++i)
#pragma unroll
        for (int r = 0; r < 4; ++r) {
            float e = __expf(E[i][r] * scale - Mr[r]);
            E[i][r] = e;
            sum[r] += e;
        }
#pragma unroll
    for (int r = 0; r < 4; ++r)
#pragma unroll
        for (int dd = 1; dd < 16; dd <<= 1) sum[r] += __shfl_xor(sum[r], dd);
    if (ln == 0) {
#pragma unroll
        for (int r = 0; r < 4; ++r) psum[sh * 32 + rowb + r] = sum[r];
    }
    __syncthreads();
    float inv[4];
#pragma unroll
    for (int r = 0; r < 4; ++r) inv[r] = 1.0f / (psum[rowb + r] + psum[32 + rowb + r]);
#pragma unroll
    for (int i = 0; i < 9; ++i) {
        const int col = sh * 144 + i * 16 + ln;
#pragma unroll
        for (int r = 0; r < 4; ++r)
            P[(rowb + r) * PROW + col] = (short)f2bf(E[i][r] * inv[r]);
    }
    __syncthreads();

    s16x8 pa[9];
#pragma unroll
    for (int kg = 0; kg < 9; ++kg)
        pa[kg] = *(const s16x8*)(P + (th * 16 + ln) * PROW + kg * 32 + g * 8);

    float maskv[4], rmax[4];
#pragma unroll
    for (int r = 0; r < 4; ++r) {
        maskv[r] = Mask[(size_t)b * T_DIM + t0 + rowb + r];
        rmax[r]  = -INFINITY;
    }

    for (int cc = 0; cc < C_DIM / 64; ++cc) {
        __syncthreads();
        for (int i2 = tid; i2 < 64 * 36; i2 += 256) {
            const int cr = i2 / 36, un = i2 - cr * 36;
            const int sb = min(s_lo + un * 8, T_DIM - 8);
            uint4 x = *(const uint4*)(Vtb + (size_t)(cc * 64 + cr) * T_DIM + sb);
            *(uint4*)(Vl + cr * PROW + un * 8) = x;
        }
        __syncthreads();
#pragma unroll
        for (int nbi = 0; nbi < 2; ++nbi) {
            const int crow = sh * 32 + nbi * 16 + ln;
            f32x4 O = zed;
#pragma unroll
            for (int kg = 0; kg < 9; ++kg) {
                s16x8 bv = *(const s16x8*)(Vl + crow * PROW + kg * 32 + g * 8);
                O = __builtin_amdgcn_mfma_f32_16x16x32_bf16(pa[kg], bv, O, 0, 0, 0);
            }
#pragma unroll
            for (int r = 0; r < 4; ++r)
                rmax[r] = fmaxf(rmax[r], O[r] * maskv[r]);
        }
    }
#pragma unroll
    for (int r = 0; r < 4; ++r)
#pragma unroll
        for (int dd = 1; dd < 16; dd <<= 1) rmax[r] = fmaxf(rmax[r], __shfl_xor(rmax[r], dd));
    if (ln == 0) {
#pragma unroll
        for (int r = 0; r < 4; ++r) red[sh * 32 + rowb + r] = rmax[r];
    }
    __syncthreads();
    if (tid < 32)
        wsrow[(size_t)b * T_DIM + t0 + tid] = fmaxf(red[tid], red[32 + tid]);
}

// out[b] = sum_t ws[b][t]
__global__ void reduce_b(const float* __restrict__ ws, float* __restrict__ out)
{
    const int b = blockIdx.x;
    float s = 0.f;
    for (int t = threadIdx.x; t < T_DIM; t += 256) s += ws[(size_t)b * T_DIM + t];
#pragma unroll
    for (int dd = 32; dd > 0; dd >>= 1) s += __shfl_xor(s, dd);
    __shared__ float acc[4];
    if ((threadIdx.x & 63) == 0) acc[threadIdx.x >> 6] = s;
    __syncthreads();
    if (threadIdx.x == 0) out[b] = acc[0] + acc[1] + acc[2] + acc[3];
}

extern "C" void kernel_launch(void* const* d_in, const int* in_sizes, int n_in,
                              void* d_out, int out_size, void* d_ws, size_t ws_size,
                              hipStream_t stream)
{
    const float* Q    = (const float*)d_in[0];
    const float* K    = (const float*)d_in[1];
    const float* V    = (const float*)d_in[2];
    const float* Mask = (const float*)d_in[3];
    const int*   m    = (const int*)d_in[4];
    float* out = (float*)d_out;

    const size_t frag_bytes = (size_t)B_DIM * T_DIM * C_DIM * 2;   // 33,554,432 per tensor
    const size_t need_main  = 2 * frag_bytes + (size_t)B_DIM * T_DIM * 4;

    if (ws_size >= need_main) {
        unsigned short* Kt  = (unsigned short*)d_ws;
        unsigned short* Vtt = (unsigned short*)((char*)d_ws + frag_bytes);
        float* wsrow = (float*)((char*)d_ws + 2 * frag_bytes);
        tile_k<<<dim3(128, B_DIM), 256, 0, stream>>>(K, Kt);
        transpose_vx<<<dim3(T_DIM / 64, C_DIM / 64, B_DIM), 256, 0, stream>>>(V, Vtt, 1);
        attn_band_tiled<<<dim3((T_DIM / TB) * B_DIM), 256, 0, stream>>>(Q, Kt, Vtt, Mask, m, wsrow);
        reduce_b<<<B_DIM, 256, 0, stream>>>(wsrow, out);
    } else {
        unsigned short* Vt = (unsigned short*)d_ws;
        float* wsrow = (float*)((char*)d_ws + frag_bytes);
        transpose_vx<<<dim3(T_DIM / 64, C_DIM / 64, B_DIM), 256, 0, stream>>>(V, Vt, 0);
        attn_band_mfma<<<dim3((T_DIM / TB) * B_DIM), 256, 0, stream>>>(Q, K, Vt, Mask, m, wsrow);
        reduce_b<<<B_DIM, 256, 0, stream>>>(wsrow, out);
    }
}

// Round 17
// 110.099 us; speedup vs baseline: 1.3654x; 1.3654x over previous
//
#include <hip/hip_runtime.h>
#include <math.h>

#define T_DIM 2048
#define C_DIM 1024
#define B_DIM 8
#define TB    32
#define KROW  72      // bf16 elems per Kc/Qc row (64 + 8 pad)  [fallback kernel]
#define PROW  296     // bf16 elems per P row (288 + 8 pad)

typedef float f32x4 __attribute__((ext_vector_type(4)));
typedef short s16x8 __attribute__((ext_vector_type(8)));

__device__ __forceinline__ unsigned short f2bf(float x) {
    union { float f; unsigned u; } v; v.f = x;
    unsigned r = v.u + 0x7fffu + ((v.u >> 16) & 1u);
    return (unsigned short)(r >> 16);
}
__device__ __forceinline__ unsigned pk2(float a, float b) {
    return (unsigned)f2bf(a) | ((unsigned)f2bf(b) << 16);
}

// async 16B/lane global->LDS DMA (wave-uniform LDS base + lane*16; per-lane global src)
__device__ __forceinline__ void gll16(const void* g, void* l) {
    __builtin_amdgcn_global_load_lds(
        (const __attribute__((address_space(1))) unsigned int*)g,
        (__attribute__((address_space(3))) unsigned int*)l,
        16, 0, 0);
}

// ============ fused pre-pass: Q conv (stream) | K tiler | V transpose — all verified patterns ============
// grid (1664, B): bx<1024 conv_q chunk; bx<1152 K tile bx-1024; else V tile vi=bx-1152.
// Qb  [b][t][c] bf16 row-major (conv_k pattern)
// Kt  [b][tile][kk][lane][8]: elem = K[b][tile*16+(l&15)][kk*32+(l>>4)*8+j]
// Vtt [b][ct][sg][lane][8]:   elem = V[b][sg*32+(l>>4)*8+j][ct*16+(l&15)]
__global__ __launch_bounds__(256)
void prep_all(const float* __restrict__ Q, const float* __restrict__ K,
              const float* __restrict__ V, unsigned short* __restrict__ Qb,
              unsigned short* __restrict__ Kt, unsigned short* __restrict__ Vtt)
{
    __shared__ float buf[64 * 67];   // V branch only
    const int bx = blockIdx.x, b = blockIdx.y, tid = threadIdx.x;

    if (bx < 1024) {
        // ---- Q: pure streaming f32 -> bf16, row-major preserved ----
        const size_t base = (size_t)b * T_DIM * C_DIM + (size_t)bx * 2048 + (size_t)tid * 8;
        const float4* src = (const float4*)(Q + base);
        float4 x = src[0], y = src[1];
        uint4 o;
        o.x = pk2(x.x, x.y); o.y = pk2(x.z, x.w);
        o.z = pk2(y.x, y.y); o.w = pk2(y.z, y.w);
        *(uint4*)(Qb + base) = o;
    } else if (bx < 1152) {
        // ---- K: fragment-major tiler (r5/r13-verified) ----
        const int tile = bx - 1024;
        const int w = tid >> 6, l = tid & 63, g = l >> 4, ln = l & 15;
        const float* src_row = K + (size_t)(b * T_DIM + tile * 16 + ln) * C_DIM;
#pragma unroll
        for (int kki = 0; kki < 8; ++kki) {
            const int kk = kki * 4 + w;
            const float4* p = (const float4*)(src_row + kk * 32 + g * 8);
            float4 x = p[0], y = p[1];
            uint4 o;
            o.x = pk2(x.x, x.y); o.y = pk2(x.z, x.w);
            o.z = pk2(y.x, y.y); o.w = pk2(y.z, y.w);
            *(uint4*)(Kt + (size_t)(((b * 128 + tile) * 32 + kk) * 64 + l) * 8) = o;
        }
    } else {
        // ---- V: 64x64 transpose + frag emit (transpose_vx verbatim) ----
        const int vi = bx - 1152;               // 0..511
        const int t0 = (vi & 31) * 64;
        const int c0 = (vi >> 5) * 64;
        const float* Vb = V + (size_t)b * T_DIM * C_DIM;

        for (int i = tid; i < 64 * 64; i += 256) {
            const int r = i >> 6, c = i & 63;
            buf[r * 67 + c] = Vb[(size_t)(t0 + r) * C_DIM + c0 + c];
        }
        __syncthreads();
        const int t8 = tid & 7;
        const int cl = tid >> 3;
#pragma unroll
        for (int half = 0; half < 2; ++half) {
            const int c_loc = cl + half * 32;
            float v[8];
#pragma unroll
            for (int j = 0; j < 8; ++j) v[j] = buf[(t8 * 8 + j) * 67 + c_loc];
            uint4 o;
            o.x = pk2(v[0], v[1]); o.y = pk2(v[2], v[3]);
            o.z = pk2(v[4], v[5]); o.w = pk2(v[6], v[7]);
            const int ct = (c0 + c_loc) >> 4, lnv = c_loc & 15;
            const int g = t8 & 3, sg = (t0 >> 5) + (t8 >> 2);
            *(uint4*)(Vtt + (size_t)(((b * 64 + ct) * 64 + sg) * 64 + g * 16 + lnv) * 8) = o;
        }
    }
}

// ============ pre-pass (fallback only): V f32 -> bf16 row-major Vt[b][c][t] ============
__global__ __launch_bounds__(256)
void transpose_vx(const float* __restrict__ V, unsigned short* __restrict__ out,
                  int frag_mode)
{
    __shared__ float buf[64 * 67];
    const int t0 = blockIdx.x * 64;
    const int c0 = blockIdx.y * 64;
    const int b  = blockIdx.z;
    const float* Vb = V + (size_t)b * T_DIM * C_DIM;

    for (int i = threadIdx.x; i < 64 * 64; i += 256) {
        const int r = i >> 6, c = i & 63;
        buf[r * 67 + c] = Vb[(size_t)(t0 + r) * C_DIM + c0 + c];
    }
    __syncthreads();
    const int t8 = threadIdx.x & 7;
    const int cl = threadIdx.x >> 3;
#pragma unroll
    for (int half = 0; half < 2; ++half) {
        const int c_loc = cl + half * 32;
        float v[8];
#pragma unroll
        for (int j = 0; j < 8; ++j) v[j] = buf[(t8 * 8 + j) * 67 + c_loc];
        uint4 o;
        o.x = pk2(v[0], v[1]); o.y = pk2(v[2], v[3]);
        o.z = pk2(v[4], v[5]); o.w = pk2(v[6], v[7]);
        if (frag_mode) {
            const int ct = (c0 + c_loc) >> 4, lnv = c_loc & 15;
            const int g = t8 & 3, sg = (t0 >> 5) + (t8 >> 2);
            *(uint4*)(out + (size_t)(((b * 64 + ct) * 64 + sg) * 64 + g * 16 + lnv) * 8) = o;
        } else {
            *(uint4*)(out + (size_t)(b * C_DIM + c0 + c_loc) * T_DIM + t0 + t8 * 8) = o;
        }
    }
}

// ============ banded attention: Kt contiguous + Q bf16 row-gather (rebalanced waves),
//              64-step phase 3 with 10-slot Vbuf -> 41.7KB LDS, 3 blocks/CU ============
__global__ __launch_bounds__(256, 3)
void attn_band_tiled(const unsigned short* __restrict__ Qb,
                     const unsigned short* __restrict__ Kt,
                     const unsigned short* __restrict__ Vtt,
                     const float* __restrict__ Mask, const int* __restrict__ m_ptr,
                     float* __restrict__ wsrow)
{
    // SMEM map (shorts): phase1: Kbuf = [0, 20480) (2 bufs x 20 frags x 512)
    //                    phase2/3: P = [0, 9472); Vbuf = [9728, 19968) (2 x 10 x 512)
    __shared__ __align__(16) short SMEM[20480];   // 40,960 B
    __shared__ float pmax[64], psum[64], red[64];
    short* Kbuf = SMEM;
    short* P    = SMEM;
    short* Vbuf = SMEM + 9728;

    // XCD-bijective swizzle: each XCD owns one batch's contiguous t-range
    const int h = blockIdx.x;
    const int logical = (h & 7) * 64 + (h >> 3);
    const int b  = logical >> 6;
    const int t0 = (logical & 63) * TB;

    const int tid = threadIdx.x;
    const int w = tid >> 6, lane = tid & 63, g = lane >> 4, ln = lane & 15;
    const int th = w >> 1, sh = w & 1;
    const int m  = m_ptr[0];

    const int s_lo = max(0, t0 - m);
    const int s_hi = min(T_DIM - 1, t0 + TB - 1 + m);
    const int sg0  = s_lo >> 5;               // 32-aligned by construction

    const unsigned short* Qgb = Qb  + (size_t)b * T_DIM * C_DIM;
    const unsigned short* Ktb = Kt  + (size_t)b * 128 * 32 * 512;
    const unsigned short* Vtb = Vtt + (size_t)b * 64 * 64 * 512;

    // ---- phase 1: E = Q.K^T ----
    f32x4 E[9];
    f32x4 zed = {0.f, 0.f, 0.f, 0.f};
#pragma unroll
    for (int i = 0; i < 9; ++i) E[i] = zed;

    // rebalanced: w0: K 0-4; w1: K 5-9; w2: K 10-13 + Q tile0 (slot 18); w3: K 14-17 + Q tile1 (slot 19)
    const int nK    = (w < 2) ? 5 : 4;
    const int fbase = (w < 2) ? w * 5 : 10 + (w - 2) * 4;
#define STAGE1(KN, NB)                                                              \
    {                                                                               \
        short* dstb = Kbuf + (NB) * 10240;                                          \
        _Pragma("unroll")                                                           \
        for (int f5 = 0; f5 < 5; ++f5) {                                            \
            if (f5 < nK) {                                                          \
                const int f = fbase + f5;                                           \
                gll16(Ktb + ((size_t)(min(sg0 * 2 + f, 127) * 32 + (KN)) * 64 + lane) * 8, \
                      dstb + f * 512);                                              \
            } else if (w >= 2) {                                                    \
                const int qt = w - 2;                                               \
                gll16(Qgb + (size_t)(t0 + qt * 16 + ln) * C_DIM + (KN) * 32 + g * 8,\
                      dstb + (18 + qt) * 512);                                      \
            }                                                                       \
        }                                                                           \
    }

    STAGE1(0, 0);
    __syncthreads();

#pragma unroll 2
    for (int kk = 0; kk < 32; ++kk) {
        const int cur = kk & 1;
        if (kk < 31) STAGE1(kk + 1, cur ^ 1);
        const short* cb = Kbuf + cur * 10240;
        s16x8 aq = *(const s16x8*)(cb + (18 + th) * 512 + lane * 8);
#pragma unroll
        for (int i = 0; i < 9; ++i) {
            s16x8 bk = *(const s16x8*)(cb + (sh * 9 + i) * 512 + lane * 8);
            E[i] = __builtin_amdgcn_mfma_f32_16x16x32_bf16(aq, bk, E[i], 0, 0, 0);
        }
        __syncthreads();
    }

    // ---- phase 2: exact softmax (cross-wave over the two s-halves) ----
    const float scale = 0.03125f;   // 1/sqrt(1024)
    const int rowb = th * 16 + g * 4;
    float lm[4];
#pragma unroll
    for (int r = 0; r < 4; ++r) lm[r] = -INFINITY;
    const int s_base = s_lo + sh * 144 + ln;
#pragma unroll
    for (int i = 0; i < 9; ++i) {
        const int s = s_base + i * 16;
#pragma unroll
        for (int r = 0; r < 4; ++r) {
            const int t = t0 + rowb + r;
            int d = t - s; d = d < 0 ? -d : d;
            const bool valid = (s <= s_hi) && (d <= m);
            float e = valid ? E[i][r] : -INFINITY;
            E[i][r] = e;
            lm[r] = fmaxf(lm[r], e);
        }
    }
#pragma unroll
    for (int r = 0; r < 4; ++r)
#pragma unroll
        for (int dd = 1; dd < 16; dd <<= 1) lm[r] = fmaxf(lm[r], __shfl_xor(lm[r], dd));
    if (ln == 0) {
#pragma unroll
        for (int r = 0; r < 4; ++r) pmax[sh * 32 + rowb + r] = lm[r];
    }
    __syncthreads();
    float Mr[4], sum[4];
#pragma unroll
    for (int r = 0; r < 4; ++r) {
        Mr[r] = fmaxf(pmax[rowb + r], pmax[32 + rowb + r]) * scale;
        sum[r] = 0.f;
    }
#pragma unroll
    for (int i = 0; i < 9; ++i)
#pragma unroll
        for (int r = 0; r < 4; ++r) {
            float e = __expf(E[i][r] * scale - Mr[r]);   // -inf -> 0 exactly
            E[i][r] = e;
            sum[r] += e;
        }
#pragma unroll
    for (int r = 0; r < 4; ++r)
#pragma unroll
        for (int dd = 1; dd < 16; dd <<= 1) sum[r] += __shfl_xor(sum[r], dd);
    if (ln == 0) {
#pragma unroll
        for (int r = 0; r < 4; ++r) psum[sh * 32 + rowb + r] = sum[r];
    }
    __syncthreads();
    float inv[4];
#pragma unroll
    for (int r = 0; r < 4; ++r) inv[r] = 1.0f / (psum[rowb + r] + psum[32 + rowb + r]);
#pragma unroll
    for (int i = 0; i < 9; ++i) {
        const int col = sh * 144 + i * 16 + ln;
#pragma unroll
        for (int r = 0; r < 4; ++r)
            P[(rowb + r) * PROW + col] = (short)f2bf(E[i][r] * inv[r]);
    }
    __syncthreads();

    // ---- phase 3: O = P @ V; 64 steps (4 per q), 10-slot dbuf ----
    // step S: q=S>>2, sub=S&3.
    //  sub0: slots 0-9 = {ct q4+0 (j<5) / q4+2 (j>=5), kg=j%5}; sh consumes slots sh*5+e -> O0
    //  sub1: same +1 ct -> O1
    //  sub2: slots 0-7 = {ct q4+0/q4+2, kg=5+j%4}; sh consumes slots sh*4+e -> O0
    //  sub3: same +1 ct -> O1, then fold
    s16x8 pa[9];
#pragma unroll
    for (int kg = 0; kg < 9; ++kg)
        pa[kg] = *(const s16x8*)(P + (th * 16 + ln) * PROW + kg * 32 + g * 8);

    float maskv[4], rmax[4];
#pragma unroll
    for (int r = 0; r < 4; ++r) {
        maskv[r] = Mask[(size_t)b * T_DIM + t0 + rowb + r];
        rmax[r]  = -INFINITY;
    }

    // wave w stages: subs 0/1: slots {w, w+4, w<2 ? 8+w}; subs 2/3: slots {w, w+4}
#define STAGE3N(S, NB)                                                              \
    {                                                                               \
        const int q_ = (S) >> 2, sub_ = (S) & 3;                                    \
        short* dstb = Vbuf + (NB) * 5120;                                           \
        if (sub_ < 2) {                                                             \
            _Pragma("unroll")                                                       \
            for (int u = 0; u < 3; ++u) {                                           \
                const int j = (u < 2) ? (w + u * 4) : (8 + w);                      \
                if (u < 2 || w < 2) {                                               \
                    const int ct_ = q_ * 4 + ((j >= 5) ? 2 : 0) + sub_;             \
                    const int kg_ = j % 5;                                          \
                    gll16(Vtb + ((size_t)(ct_ * 64 + min(sg0 + kg_, 63)) * 64 + lane) * 8, \
                          dstb + j * 512);                                          \
                }                                                                   \
            }                                                                       \
        } else {                                                                    \
            _Pragma("unroll")                                                       \
            for (int u = 0; u < 2; ++u) {                                           \
                const int j = w + u * 4;                                            \
                const int ct_ = q_ * 4 + ((j >= 4) ? 2 : 0) + (sub_ - 2);           \
                const int kg_ = 5 + (j & 3);                                        \
                gll16(Vtb + ((size_t)(ct_ * 64 + min(sg0 + kg_, 63)) * 64 + lane) * 8, \
                      dstb + j * 512);                                              \
            }                                                                       \
        }                                                                           \
    }

    STAGE3N(0, 0);
    __syncthreads();

    f32x4 O0 = zed, O1 = zed;
#pragma unroll 4
    for (int S = 0; S < 64; ++S) {
        const int cur = S & 1;
        if (S < 63) STAGE3N(S + 1, cur ^ 1);
        const short* vb = Vbuf + cur * 5120;
        const int sub = S & 3;
        if (sub == 0) {
            O0 = zed; O1 = zed;
#pragma unroll
            for (int e = 0; e < 5; ++e) {
                s16x8 bv = *(const s16x8*)(vb + (sh * 5 + e) * 512 + lane * 8);
                O0 = __builtin_amdgcn_mfma_f32_16x16x32_bf16(pa[e], bv, O0, 0, 0, 0);
            }
        } else if (sub == 1) {
#pragma unroll
            for (int e = 0; e < 5; ++e) {
                s16x8 bv = *(const s16x8*)(vb + (sh * 5 + e) * 512 + lane * 8);
                O1 = __builtin_amdgcn_mfma_f32_16x16x32_bf16(pa[e], bv, O1, 0, 0, 0);
            }
        } else if (sub == 2) {
#pragma unroll
            for (int e = 0; e < 4; ++e) {
                s16x8 bv = *(const s16x8*)(vb + (sh * 4 + e) * 512 + lane * 8);
                O0 = __builtin_amdgcn_mfma_f32_16x16x32_bf16(pa[5 + e], bv, O0, 0, 0, 0);
            }
        } else {
#pragma unroll
            for (int e = 0; e < 4; ++e) {
                s16x8 bv = *(const s16x8*)(vb + (sh * 4 + e) * 512 + lane * 8);
                O1 = __builtin_amdgcn_mfma_f32_16x16x32_bf16(pa[5 + e], bv, O1, 0, 0, 0);
            }
#pragma unroll
            for (int r = 0; r < 4; ++r) {
                rmax[r] = fmaxf(rmax[r], O0[r] * maskv[r]);
                rmax[r] = fmaxf(rmax[r], O1[r] * maskv[r]);
            }
        }
        __syncthreads();
    }

#pragma unroll
    for (int r = 0; r < 4; ++r)
#pragma unroll
        for (int dd = 1; dd < 16; dd <<= 1) rmax[r] = fmaxf(rmax[r], __shfl_xor(rmax[r], dd));
    if (ln == 0) {
#pragma unroll
        for (int r = 0; r < 4; ++r) red[sh * 32 + rowb + r] = rmax[r];
    }
    __syncthreads();
    if (tid < 32)
        wsrow[(size_t)b * T_DIM + t0 + tid] = fmaxf(red[tid], red[32 + tid]);
}

// ============ fallback (round-1, verified): K/V staged per block, Vt row-major ============
__global__ __launch_bounds__(256, 2)
void attn_band_mfma(const float* __restrict__ Q, const float* __restrict__ K,
                    const unsigned short* __restrict__ Vt,
                    const float* __restrict__ Mask, const int* __restrict__ m_ptr,
                    float* __restrict__ wsrow)
{
    __shared__ __align__(16) char smem_raw[57600];
    short* SM = (short*)smem_raw;
    short* Kc = SM;
    short* Qc = SM + 288 * KROW;
    short* P  = SM;
    short* Vl = SM + 32 * PROW;
    float* pmax = (float*)(smem_raw + 56832);
    float* psum = pmax + 64;
    float* red  = psum + 64;

    const int h = blockIdx.x;
    const int logical = (h & 7) * 64 + (h >> 3);
    const int b  = logical >> 6;
    const int t0 = (logical & 63) * TB;

    const int tid = threadIdx.x;
    const int w = tid >> 6, lane = tid & 63, g = lane >> 4, ln = lane & 15;
    const int th = w >> 1, sh = w & 1;
    const int m  = m_ptr[0];

    const int s_lo = max(0, t0 - m);
    const int s_hi = min(T_DIM - 1, t0 + TB - 1 + m);

    const float* Qb = Q + (size_t)b * T_DIM * C_DIM;
    const float* Kb = K + (size_t)b * T_DIM * C_DIM;
    const unsigned short* Vtb = Vt + (size_t)b * C_DIM * T_DIM;

    f32x4 E[9];
    f32x4 zed = {0.f, 0.f, 0.f, 0.f};
#pragma unroll
    for (int i = 0; i < 9; ++i) E[i] = zed;

    for (int cc = 0; cc < C_DIM / 64; ++cc) {
        const int c0 = cc * 64;
        __syncthreads();
        for (int u = tid; u < 288 * 8; u += 256) {
            const int su = u >> 3, un = u & 7;
            const int s = min(s_lo + su, T_DIM - 1);
            const float4* src = (const float4*)(Kb + (size_t)s * C_DIM + c0 + un * 8);
            float4 x = src[0], y = src[1];
            uint4 o; o.x = pk2(x.x, x.y); o.y = pk2(x.z, x.w);
            o.z = pk2(y.x, y.y); o.w = pk2(y.z, y.w);
            *(uint4*)(Kc + su * KROW + un * 8) = o;
        }
        {
            const int su = tid >> 3, un = tid & 7;
            const float4* src = (const float4*)(Qb + (size_t)(t0 + su) * C_DIM + c0 + un * 8);
            float4 x = src[0], y = src[1];
            uint4 o; o.x = pk2(x.x, x.y); o.y = pk2(x.z, x.w);
            o.z = pk2(y.x, y.y); o.w = pk2(y.z, y.w);
            *(uint4*)(Qc + su * KROW + un * 8) = o;
        }
        __syncthreads();
        s16x8 aq[2];
#pragma unroll
        for (int kk = 0; kk < 2; ++kk)
            aq[kk] = *(const s16x8*)(Qc + (th * 16 + ln) * KROW + kk * 32 + g * 8);
#pragma unroll
        for (int i = 0; i < 9; ++i) {
            const int srow2 = (sh * 9 + i) * 16 + ln;
#pragma unroll
            for (int kk = 0; kk < 2; ++kk) {
                s16x8 bk = *(const s16x8*)(Kc + srow2 * KROW + kk * 32 + g * 8);
                E[i] = __builtin_amdgcn_mfma_f32_16x16x32_bf16(aq[kk], bk, E[i], 0, 0, 0);
            }
        }
    }

    const float scale = 0.03125f;
    const int rowb = th * 16 + g * 4;
    float lm[4];
#pragma unroll
    for (int r = 0; r < 4; ++r) lm[r] = -INFINITY;
    const int s_base = s_lo + sh * 144 + ln;
#pragma unroll
    for (int i = 0; i < 9; ++i) {
        const int s = s_base + i * 16;
#pragma unroll
        for (int r = 0; r < 4; ++r) {
            const int t = t0 + rowb + r;
            int d = t - s; d = d < 0 ? -d : d;
            const bool valid = (s <= s_hi) && (d <= m);
            float e = valid ? E[i][r] : -INFINITY;
            E[i][r] = e;
            lm[r] = fmaxf(lm[r], e);
        }
    }
#pragma unroll
    for (int r = 0; r < 4; ++r)
#pragma unroll
        for (int dd = 1; dd < 16; dd <<= 1) lm[r] = fmaxf(lm[r], __shfl_xor(lm[r], dd));
    if (ln == 0) {
#pragma unroll
        for (int r = 0; r < 4; ++r) pmax[sh * 32 + rowb + r] = lm[r];
    }
    __syncthreads();
    float Mr[4], sum[4];
#pragma unroll
    for (int r = 0; r < 4; ++r) {
        Mr[r] = fmaxf(pmax[rowb + r], pmax[32 + rowb + r]) * scale;
        sum[r] = 0.f;
    }
#pragma unroll
    for (int i = 0; i < 9; ++i)
#pragma unroll
        for (int r = 0; r < 4; ++r) {
            float e = __expf(E[i][r] * scale - Mr[r]);
            E[i][r] = e;
            sum[r] += e;
        }
#pragma unroll
    for (int r = 0; r < 4; ++r)
#pragma unroll
        for (int dd = 1; dd < 16; dd <<= 1) sum[r] += __shfl_xor(sum[r], dd);
    if (ln == 0) {
#pragma unroll
        for (int r = 0; r < 4; ++r) psum[sh * 32 + rowb + r] = sum[r];
    }
    __syncthreads();
    float inv[4];
#pragma unroll
    for (int r = 0; r < 4; ++r) inv[r] = 1.0f / (psum[rowb + r] + psum[32 + rowb + r]);
#pragma unroll
    for (int i = 0; i < 9; ++i) {
        const int col = sh * 144 + i * 16 + ln;
#pragma unroll
        for (int r = 0; r < 4; ++r)
            P[(rowb + r) * PROW + col] = (short)f2bf(E[i][r] * inv[r]);
    }
    __syncthreads();

    s16x8 pa[9];
#pragma unroll
    for (int kg = 0; kg < 9; ++kg)
        pa[kg] = *(const s16x8*)(P + (th * 16 + ln) * PROW + kg * 32 + g * 8);

    float maskv[4], rmax[4];
#pragma unroll
    for (int r = 0; r < 4; ++r) {
        maskv[r] = Mask[(size_t)b * T_DIM + t0 + rowb + r];
        rmax[r]  = -INFINITY;
    }

    for (int cc = 0; cc < C_DIM / 64; ++cc) {
        __syncthreads();
        for (int i2 = tid; i2 < 64 * 36; i2 += 256) {
            const int cr = i2 / 36, un = i2 - cr * 36;
            const int sb = min(s_lo + un * 8, T_DIM - 8);
            uint4 x = *(const uint4*)(Vtb + (size_t)(cc * 64 + cr) * T_DIM + sb);
            *(uint4*)(Vl + cr * PROW + un * 8) = x;
        }
        __syncthreads();
#pragma unroll
        for (int nbi = 0; nbi < 2; ++nbi) {
            const int crow = sh * 32 + nbi * 16 + ln;
            f32x4 O = zed;
#pragma unroll
            for (int kg = 0; kg < 9; ++kg) {
                s16x8 bv = *(const s16x8*)(Vl + crow * PROW + kg * 32 + g * 8);
                O = __builtin_amdgcn_mfma_f32_16x16x32_bf16(pa[kg], bv, O, 0, 0, 0);
            }
#pragma unroll
            for (int r = 0; r < 4; ++r)
                rmax[r] = fmaxf(rmax[r], O[r] * maskv[r]);
        }
    }
#pragma unroll
    for (int r = 0; r < 4; ++r)
#pragma unroll
        for (int dd = 1; dd < 16; dd <<= 1) rmax[r] = fmaxf(rmax[r], __shfl_xor(rmax[r], dd));
    if (ln == 0) {
#pragma unroll
        for (int r = 0; r < 4; ++r) red[sh * 32 + rowb + r] = rmax[r];
    }
    __syncthreads();
    if (tid < 32)
        wsrow[(size_t)b * T_DIM + t0 + tid] = fmaxf(red[tid], red[32 + tid]);
}

// out[b] = sum_t ws[b][t]
__global__ void reduce_b(const float* __restrict__ ws, float* __restrict__ out)
{
    const int b = blockIdx.x;
    float s = 0.f;
    for (int t = threadIdx.x; t < T_DIM; t += 256) s += ws[(size_t)b * T_DIM + t];
#pragma unroll
    for (int dd = 32; dd > 0; dd >>= 1) s += __shfl_xor(s, dd);
    __shared__ float acc[4];
    if ((threadIdx.x & 63) == 0) acc[threadIdx.x >> 6] = s;
    __syncthreads();
    if (threadIdx.x == 0) out[b] = acc[0] + acc[1] + acc[2] + acc[3];
}

extern "C" void kernel_launch(void* const* d_in, const int* in_sizes, int n_in,
                              void* d_out, int out_size, void* d_ws, size_t ws_size,
                              hipStream_t stream)
{
    const float* Q    = (const float*)d_in[0];
    const float* K    = (const float*)d_in[1];
    const float* V    = (const float*)d_in[2];
    const float* Mask = (const float*)d_in[3];
    const int*   m    = (const int*)d_in[4];
    float* out = (float*)d_out;

    const size_t frag_bytes = (size_t)B_DIM * T_DIM * C_DIM * 2;   // 33,554,432 per tensor
    const size_t need_main  = 3 * frag_bytes + (size_t)B_DIM * T_DIM * 4;

    if (ws_size >= need_main) {
        unsigned short* Qb  = (unsigned short*)d_ws;
        unsigned short* Kt  = (unsigned short*)((char*)d_ws + frag_bytes);
        unsigned short* Vtt = (unsigned short*)((char*)d_ws + 2 * frag_bytes);
        float* wsrow = (float*)((char*)d_ws + 3 * frag_bytes);
        prep_all<<<dim3(1664, B_DIM), 256, 0, stream>>>(Q, K, V, Qb, Kt, Vtt);
        attn_band_tiled<<<dim3((T_DIM / TB) * B_DIM), 256, 0, stream>>>(Qb, Kt, Vtt, Mask, m, wsrow);
        reduce_b<<<B_DIM, 256, 0, stream>>>(wsrow, out);
    } else {
        unsigned short* Vt = (unsigned short*)d_ws;
        float* wsrow = (float*)((char*)d_ws + frag_bytes);
        transpose_vx<<<dim3(T_DIM / 64, C_DIM / 64, B_DIM), 256, 0, stream>>>(V, Vt, 0);
        attn_band_mfma<<<dim3((T_DIM / TB) * B_DIM), 256, 0, stream>>>(Q, K, Vt, Mask, m, wsrow);
        reduce_b<<<B_DIM, 256, 0, stream>>>(wsrow, out);
    }
}